// Round 7
// baseline (923.653 us; speedup 1.0000x reference)
//
#include <hip/hip_runtime.h>
#include <math.h>

// Problem constants
// x: (B=2, C=32, D=96, H=96, W=96) fp32
// out: (2, 32, 48, 48, 48) fp32
#define HS 0.35355339059327373f   /* 1/(2*sqrt(2)) — 3-stage Haar scale */
#define NSPAT 110592              /* 48^3 */
#define NBN   221184              /* B * 48^3 */

// ---------------------------------------------------------------------------
// K1: per-(b,c) parity sums S[b][c][p][q][r] = sum over x[2i+p][2j+q][2l+r]
// One block per (b,c,d)-plane. (unchanged — streams x once, ~40 us ~ HBM floor)
// ---------------------------------------------------------------------------
__global__ __launch_bounds__(256) void k1_parity(const float* __restrict__ x,
                                                 float* __restrict__ S) {
    int blk = blockIdx.x;            // (b*32+c)*96 + d
    int d   = blk % 96;
    int bc  = blk / 96;
    const float4* x4 = (const float4*)x + (long)blk * 2304;
    int tid = threadIdx.x;
    float aE0 = 0.f, aO0 = 0.f, aE1 = 0.f, aO1 = 0.f;  // [q][r]
#pragma unroll
    for (int i = 0; i < 9; ++i) {
        int f = tid + i * 256;           // < 2304
        float4 v = x4[f];
        int h = f / 24;                  // row within plane (const-div -> magic mul)
        float e = v.x + v.z, o = v.y + v.w;
        if (h & 1) { aE1 += e; aO1 += o; }
        else       { aE0 += e; aO0 += o; }
    }
#pragma unroll
    for (int m = 32; m; m >>= 1) {
        aE0 += __shfl_xor(aE0, m, 64); aO0 += __shfl_xor(aO0, m, 64);
        aE1 += __shfl_xor(aE1, m, 64); aO1 += __shfl_xor(aO1, m, 64);
    }
    __shared__ float red[4][4];
    int lane = tid & 63, wave = tid >> 6;
    if (lane == 0) { red[wave][0] = aE0; red[wave][1] = aO0;
                     red[wave][2] = aE1; red[wave][3] = aO1; }
    __syncthreads();
    if (tid < 4) {
        float v = red[0][tid] + red[1][tid] + red[2][tid] + red[3][tid];
        int q = tid >> 1, r = tid & 1, p = d & 1;
        atomicAdd(&S[bc * 8 + p * 4 + q * 2 + r], v);
    }
}

// ---------------------------------------------------------------------------
// K2: band means -> two attention MLPs -> effective fuse matrix.
// 16 blocks; lane-parallel dots + shfl tree reduce; A[b][c][o][pqr].
// (unchanged)
// ---------------------------------------------------------------------------
__global__ __launch_bounds__(256) void k2_attn(
        const float* __restrict__ S,
        const float* __restrict__ w1l, const float* __restrict__ w2l,
        const float* __restrict__ w1h, const float* __restrict__ w2h,
        const float* __restrict__ wf, float* __restrict__ A) {
    int b = blockIdx.x >> 3, slice = blockIdx.x & 7;
    int tid = threadIdx.x;
    __shared__ float mlow[32], mhigh[224], h1l[2], h1h[14], ylow[32], yhigh[224];
    const float* Sb = S + b * 256;
    const float MS = HS / (float)NSPAT;   // subband mean scale

    {
        int c = tid >> 3, k = tid & 7;
        float s = 0.f;
        if (k == 0) {
#pragma unroll
            for (int j = 0; j < 8; ++j) s += Sb[c * 8 + j];
            mlow[c] = s * MS;
        } else {
#pragma unroll
            for (int j = 0; j < 8; ++j) {
                float sg = (__popc(j & k) & 1) ? -1.f : 1.f;
                s += sg * Sb[c * 8 + j];
            }
            mhigh[c * 7 + (k - 1)] = s * MS;
        }
    }
    __syncthreads();
    if (tid < 224) {            // h1h[g] = relu(w1h[g,:224] . mhigh)
        int g = tid >> 4, l = tid & 15;
        float p = 0.f;
#pragma unroll
        for (int i = 0; i < 14; ++i)
            p += w1h[g * 224 + l * 14 + i] * mhigh[l * 14 + i];
#pragma unroll
        for (int m = 8; m; m >>= 1) p += __shfl_xor(p, m, 64);
        if (l == 0) h1h[g] = fmaxf(p, 0.f);
    } else {                    // tid in [224,256): h1l[j]
        int j = (tid - 224) >> 4, l = tid & 15;
        float p = w1l[j * 32 + l] * mlow[l] + w1l[j * 32 + 16 + l] * mlow[16 + l];
#pragma unroll
        for (int m = 8; m; m >>= 1) p += __shfl_xor(p, m, 64);
        if (l == 0) h1l[j] = fmaxf(p, 0.f);
    }
    __syncthreads();
    if (tid < 32) {
        float s = w2l[tid * 2] * h1l[0] + w2l[tid * 2 + 1] * h1l[1];
        ylow[tid] = 1.f / (1.f + expf(-s));
    } else {
        int i = tid - 32;       // < 224
        float s = 0.f;
#pragma unroll
        for (int j = 0; j < 14; ++j) s += w2h[i * 14 + j] * h1h[j];
        yhigh[i] = 1.f / (1.f + expf(-s));
    }
    __syncthreads();
#pragma unroll
    for (int it = 0; it < 4; ++it) {
        int idx = slice * 1024 + it * 256 + tid;       // < 8192
        int o = idx >> 8, c = (idx >> 3) & 31, pqr = idx & 7;
        float a = wf[o * 256 + c] * ylow[c];
#pragma unroll
        for (int k = 0; k < 7; ++k) {
            float sg = (__popc(pqr & (k + 1)) & 1) ? -1.f : 1.f;
            a += sg * wf[o * 256 + 32 + c * 7 + k] * yhigh[c * 7 + k];
        }
        A[b * 8192 + c * 256 + o * 8 + pqr] = a * HS;
    }
}

// ---------------------------------------------------------------------------
// K3 (main): z[b,o,od,oh,ow] = sum_{c,pqr} A[b,o,c,pqr] * x[b,c,2od+p,2oh+q,2ow+r]
// R9 (resubmitted R10 — broker timeout, never ran): SPLIT-K on the proven
// R7 shape. R8's 4px variant spilled accs (WRITE_SIZE 374MB scratch, occ
// 11%) -> reverted. R7/R3 both sat at ~112us with ~20-30% per-wave issue
// duty at 42% occupancy ceiling (grid-limited 3.375 waves/SIMD) regardless
// of A path (s_load vs LDS) -> limiter is latency hiding, not A access.
// Fix: block 384 = 2 kparts x 192; kpart w computes c in [16w,16w+16) for
// the same 8x24 px tile -> total waves x2 (~5-6.75/SIMD schedulable).
// Per-wave structure (2px, 32 accs, ping-pong, LDS-A) identical to R7.
// Epilogue: kpart1 folds partials into kpart0 via [16][192] LDS (2 rounds,
// conflict-free, uniform barriers); kpart0 writes z + BN partials.
// __launch_bounds__(384,4): VGPR cap 128, need ~90 -> no spill.
// ---------------------------------------------------------------------------
#define K3_LOAD(s, cc) { int i4_ = base + (cc) * 221184;                     \
    s##0 = x4[i4_]; s##1 = x4[i4_ + 24];                                     \
    s##2 = x4[i4_ + 2304]; s##3 = x4[i4_ + 2328]; }

#define K3_FMA(s, Ac) {                                                      \
    _Pragma("unroll")                                                        \
    for (int o = 0; o < 16; ++o) {                                           \
        const float* Ao_ = (Ac) + o * 8;   /* uniform LDS broadcast */       \
        float a0 = Ao_[0], a1 = Ao_[1], a2 = Ao_[2], a3 = Ao_[3];            \
        float a4 = Ao_[4], a5 = Ao_[5], a6 = Ao_[6], a7 = Ao_[7];            \
        acc0[o] += a0 * (s##0).x + a1 * (s##0).y + a2 * (s##1).x             \
                 + a3 * (s##1).y + a4 * (s##2).x + a5 * (s##2).y             \
                 + a6 * (s##3).x + a7 * (s##3).y;                            \
        acc1[o] += a0 * (s##0).z + a1 * (s##0).w + a2 * (s##1).z             \
                 + a3 * (s##1).w + a4 * (s##2).z + a5 * (s##2).w             \
                 + a6 * (s##3).z + a7 * (s##3).w;                            \
    } }

__global__ __launch_bounds__(384, 4) void k3_main(const float* __restrict__ x,
                                                  const float* __restrict__ A,
                                                  float* __restrict__ z,
                                                  float* __restrict__ bnSum,
                                                  float* __restrict__ bnSq) {
    __shared__ float sA[4096];          // og-slice: [c<32][o'<16][pqr<8]
    __shared__ float redbuf[16][192];   // split-K fold buffer (12 KB)
    __shared__ float red[3][32];        // BN wave partials (kpart 0 waves)
    int blk  = blockIdx.x;             // [resthi | og(1b) | restlo(3b)]
    int og   = (blk >> 3) & 1;
    int rest = (blk & 7) | ((blk >> 4) << 3);   // 0..575
    int ohg  = rest % 6;
    int tmp  = rest / 6;
    int od   = tmp % 48;
    int b    = tmp / 48;
    int tid   = threadIdx.x;
    int kpart = tid / 192;             // 0/1: K-partition
    int tl    = tid % 192;
    int row = tl / 24;                 // 0..7
    int t   = tl % 24;                 // ow-pair: outputs 2t, 2t+1
    int oh  = ohg * 8 + row;
    int cbase = kpart * 16;            // this wave-group's channel range

    const float4* x4 = (const float4*)x;
    // float4 index for (b, c, 2od+p, 2oh+q, 4t): channel stride 96^3/4 = 221184
    int base = (((b * 32) * 96 + 2 * od) * 96 + 2 * oh) * 24 + t;

    // stage A og-slice into LDS: sA[c*128 + o'*8 + pqr] = A[b][c][og*16+o'][pqr]
    {
        const float4* A4 = (const float4*)A;
        int srcbase = b * 2048 + og * 32;     // float4 units
        float4* sA4 = (float4*)sA;
        for (int s = tid; s < 1024; s += 384) {
            int c = s >> 5, j = s & 31;
            sA4[s] = A4[srcbase + c * 64 + j];
        }
    }

    float acc0[16], acc1[16];
#pragma unroll
    for (int o = 0; o < 16; ++o) { acc0[o] = 0.f; acc1[o] = 0.f; }

    float4 pa0, pa1, pa2, pa3, pb0, pb1, pb2, pb3;
    K3_LOAD(pa, cbase);                // x prefetch overlaps A staging
    __syncthreads();

    for (int c = 0; c < 16; c += 2) {
        K3_LOAD(pb, cbase + c + 1);
        const float* Ac = sA + (cbase + c) * 128;
        K3_FMA(pa, Ac);
        if (c + 2 < 16) K3_LOAD(pa, cbase + c + 2);
        K3_FMA(pb, Ac + 128);
    }

    // fold kpart1 partials into kpart0 (2 rounds x 16 floats, uniform barriers)
#pragma unroll
    for (int j = 0; j < 2; ++j) {
        if (kpart == 1) {
#pragma unroll
            for (int i = 0; i < 8; ++i) {
                redbuf[2 * i][tl]     = acc0[8 * j + i];
                redbuf[2 * i + 1][tl] = acc1[8 * j + i];
            }
        }
        __syncthreads();
        if (kpart == 0) {
#pragma unroll
            for (int i = 0; i < 8; ++i) {
                acc0[8 * j + i] += redbuf[2 * i][tl];
                acc1[8 * j + i] += redbuf[2 * i + 1][tl];
            }
        }
        __syncthreads();
    }

    if (kpart == 0) {
        // write z (staged in d_out), coalesced float2 per o
        float2* z2 = (float2*)z;
#pragma unroll
        for (int o = 0; o < 16; ++o) {
            int zi = (((b * 32 + og * 16 + o) * 48 + od) * 48 + oh) * 24 + t;
            z2[zi] = make_float2(acc0[o], acc1[o]);
        }
        // BN partial sums for this block's 16 channels
        int lane = tid & 63, wave = tid >> 6;   // wave 0..2
#pragma unroll
        for (int o = 0; o < 16; ++o) {
            float sv = acc0[o] + acc1[o];
            float qv = acc0[o] * acc0[o] + acc1[o] * acc1[o];
#pragma unroll
            for (int m = 32; m; m >>= 1) {
                sv += __shfl_xor(sv, m, 64);
                qv += __shfl_xor(qv, m, 64);
            }
            if (lane == 0) { red[wave][o] = sv; red[wave][16 + o] = qv; }
        }
    }
    __syncthreads();
    if (tid < 32) {
        float v = red[0][tid] + red[1][tid] + red[2][tid];
        if (tid < 16) atomicAdd(&bnSum[og * 16 + tid], v);
        else          atomicAdd(&bnSq[og * 16 + tid - 16], v);
    }
}

// ---------------------------------------------------------------------------
// K5: BN finalize (per-block recompute) + normalize + ReLU, in place over
// z (= d_out). 1769472 float4s exactly. b_fuse cancels under BN mean-subtract.
// ---------------------------------------------------------------------------
__global__ __launch_bounds__(256) void k5_norm(float* __restrict__ z,
                                               const float* __restrict__ bnSum,
                                               const float* __restrict__ bnSq,
                                               const float* __restrict__ gamma,
                                               const float* __restrict__ beta) {
    __shared__ float s_sc[32], s_sh[32];
    int tid = threadIdx.x;
    if (tid < 32) {
        const float invN = 1.f / (float)NBN;
        float mean = bnSum[tid] * invN;
        float var  = bnSq[tid] * invN - mean * mean;
        float inv  = rsqrtf(var + 1e-5f);
        float sc   = gamma[tid] * inv;
        s_sc[tid] = sc;
        s_sh[tid] = beta[tid] - mean * sc;
    }
    int i = blockIdx.x * 256 + tid;                // float4 index
    float4* z4 = (float4*)z;
    float4 v = z4[i];                              // load before barrier (indep)
    __syncthreads();
    int o = (i / 27648) & 31;                      // 27648 = 48^3/4
    float sc = s_sc[o], sh = s_sh[o];
    v.x = fmaxf(v.x * sc + sh, 0.f);
    v.y = fmaxf(v.y * sc + sh, 0.f);
    v.z = fmaxf(v.z * sc + sh, 0.f);
    v.w = fmaxf(v.w * sc + sh, 0.f);
    z4[i] = v;
}

extern "C" void kernel_launch(void* const* d_in, const int* in_sizes, int n_in,
                              void* d_out, int out_size, void* d_ws, size_t ws_size,
                              hipStream_t stream) {
    const float* x    = (const float*)d_in[0];
    const float* w1l  = (const float*)d_in[1];
    const float* w2l  = (const float*)d_in[2];
    const float* w1h  = (const float*)d_in[3];
    const float* w2h  = (const float*)d_in[4];
    const float* wf   = (const float*)d_in[5];
    // d_in[6] = b_fuse: cancels exactly under training-mode BN (mean subtract)
    const float* gamma = (const float*)d_in[7];
    const float* beta  = (const float*)d_in[8];
    float* out = (float*)d_out;

    float* ws    = (float*)d_ws;
    float* S     = ws;          // 512 floats (zeroed)
    float* bnSum = ws + 512;    // 32 (zeroed)
    float* bnSq  = ws + 544;    // 32 (zeroed)
    float* A     = ws + 1024;   // 16384 floats, layout [b][c][o][pqr]

    hipMemsetAsync(d_ws, 0, 576 * sizeof(float), stream);
    k1_parity<<<6144, 256, 0, stream>>>(x, S);
    k2_attn<<<16, 256, 0, stream>>>(S, w1l, w2l, w1h, w2h, wf, A);
    k3_main<<<1152, 384, 0, stream>>>(x, A, out, bnSum, bnSq);
    k5_norm<<<6912, 256, 0, stream>>>(out, bnSum, bnSq, gamma, beta);
}

// Round 8
// 436.129 us; speedup vs baseline: 2.1178x; 2.1178x over previous
//
#include <hip/hip_runtime.h>
#include <math.h>

// Problem constants
// x: (B=2, C=32, D=96, H=96, W=96) fp32
// out: (2, 32, 48, 48, 48) fp32
#define HS 0.35355339059327373f   /* 1/(2*sqrt(2)) — 3-stage Haar scale */
#define NSPAT 110592              /* 48^3 */
#define NBN   221184              /* B * 48^3 */

// ---------------------------------------------------------------------------
// K1: per-(b,c) parity sums S[b][c][p][q][r] = sum over x[2i+p][2j+q][2l+r]
// One block per (b,c,d)-plane. (unchanged — streams x once, ~40 us ~ HBM floor)
// ---------------------------------------------------------------------------
__global__ __launch_bounds__(256) void k1_parity(const float* __restrict__ x,
                                                 float* __restrict__ S) {
    int blk = blockIdx.x;            // (b*32+c)*96 + d
    int d   = blk % 96;
    int bc  = blk / 96;
    const float4* x4 = (const float4*)x + (long)blk * 2304;
    int tid = threadIdx.x;
    float aE0 = 0.f, aO0 = 0.f, aE1 = 0.f, aO1 = 0.f;  // [q][r]
#pragma unroll
    for (int i = 0; i < 9; ++i) {
        int f = tid + i * 256;           // < 2304
        float4 v = x4[f];
        int h = f / 24;                  // row within plane (const-div -> magic mul)
        float e = v.x + v.z, o = v.y + v.w;
        if (h & 1) { aE1 += e; aO1 += o; }
        else       { aE0 += e; aO0 += o; }
    }
#pragma unroll
    for (int m = 32; m; m >>= 1) {
        aE0 += __shfl_xor(aE0, m, 64); aO0 += __shfl_xor(aO0, m, 64);
        aE1 += __shfl_xor(aE1, m, 64); aO1 += __shfl_xor(aO1, m, 64);
    }
    __shared__ float red[4][4];
    int lane = tid & 63, wave = tid >> 6;
    if (lane == 0) { red[wave][0] = aE0; red[wave][1] = aO0;
                     red[wave][2] = aE1; red[wave][3] = aO1; }
    __syncthreads();
    if (tid < 4) {
        float v = red[0][tid] + red[1][tid] + red[2][tid] + red[3][tid];
        int q = tid >> 1, r = tid & 1, p = d & 1;
        atomicAdd(&S[bc * 8 + p * 4 + q * 2 + r], v);
    }
}

// ---------------------------------------------------------------------------
// K2: band means -> two attention MLPs -> effective fuse matrix.
// 16 blocks; lane-parallel dots + shfl tree reduce; A[b][c][o][pqr].
// (unchanged)
// ---------------------------------------------------------------------------
__global__ __launch_bounds__(256) void k2_attn(
        const float* __restrict__ S,
        const float* __restrict__ w1l, const float* __restrict__ w2l,
        const float* __restrict__ w1h, const float* __restrict__ w2h,
        const float* __restrict__ wf, float* __restrict__ A) {
    int b = blockIdx.x >> 3, slice = blockIdx.x & 7;
    int tid = threadIdx.x;
    __shared__ float mlow[32], mhigh[224], h1l[2], h1h[14], ylow[32], yhigh[224];
    const float* Sb = S + b * 256;
    const float MS = HS / (float)NSPAT;   // subband mean scale

    {
        int c = tid >> 3, k = tid & 7;
        float s = 0.f;
        if (k == 0) {
#pragma unroll
            for (int j = 0; j < 8; ++j) s += Sb[c * 8 + j];
            mlow[c] = s * MS;
        } else {
#pragma unroll
            for (int j = 0; j < 8; ++j) {
                float sg = (__popc(j & k) & 1) ? -1.f : 1.f;
                s += sg * Sb[c * 8 + j];
            }
            mhigh[c * 7 + (k - 1)] = s * MS;
        }
    }
    __syncthreads();
    if (tid < 224) {            // h1h[g] = relu(w1h[g,:224] . mhigh)
        int g = tid >> 4, l = tid & 15;
        float p = 0.f;
#pragma unroll
        for (int i = 0; i < 14; ++i)
            p += w1h[g * 224 + l * 14 + i] * mhigh[l * 14 + i];
#pragma unroll
        for (int m = 8; m; m >>= 1) p += __shfl_xor(p, m, 64);
        if (l == 0) h1h[g] = fmaxf(p, 0.f);
    } else {                    // tid in [224,256): h1l[j]
        int j = (tid - 224) >> 4, l = tid & 15;
        float p = w1l[j * 32 + l] * mlow[l] + w1l[j * 32 + 16 + l] * mlow[16 + l];
#pragma unroll
        for (int m = 8; m; m >>= 1) p += __shfl_xor(p, m, 64);
        if (l == 0) h1l[j] = fmaxf(p, 0.f);
    }
    __syncthreads();
    if (tid < 32) {
        float s = w2l[tid * 2] * h1l[0] + w2l[tid * 2 + 1] * h1l[1];
        ylow[tid] = 1.f / (1.f + expf(-s));
    } else {
        int i = tid - 32;       // < 224
        float s = 0.f;
#pragma unroll
        for (int j = 0; j < 14; ++j) s += w2h[i * 14 + j] * h1h[j];
        yhigh[i] = 1.f / (1.f + expf(-s));
    }
    __syncthreads();
#pragma unroll
    for (int it = 0; it < 4; ++it) {
        int idx = slice * 1024 + it * 256 + tid;       // < 8192
        int o = idx >> 8, c = (idx >> 3) & 31, pqr = idx & 7;
        float a = wf[o * 256 + c] * ylow[c];
#pragma unroll
        for (int k = 0; k < 7; ++k) {
            float sg = (__popc(pqr & (k + 1)) & 1) ? -1.f : 1.f;
            a += sg * wf[o * 256 + 32 + c * 7 + k] * yhigh[c * 7 + k];
        }
        A[b * 8192 + c * 256 + o * 8 + pqr] = a * HS;
    }
}

// ---------------------------------------------------------------------------
// K3 (main): z[b,o,od,oh,ow] = sum_{c,pqr} A[b,o,c,pqr] * x[b,c,2od+p,2oh+q,2ow+r]
// R11: O-SPLIT under the 64-VGPR tier. Evidence R6/R8/R9: whenever register
// NEED > 64, hipcc pins a low tier (64/128) and spills accs -> GBs of
// scratch (R9: WRITE 1.4GB, 605us). R7 (need ~128) worked but sat at 4-wave
// tier, grid-capped 3.375 waves/SIMD, ~25% issue duty, 112us. Fix: make
// need < 64 so the 8-wave tier fits with ZERO spill:
//  - block 384 = 2 o-groups x 192 over the same 8x24 px tile; each thread
//    computes 8 o x 2 px = 16 accs (o-split is output-disjoint: no fold).
//  - single-buffer x loads, "#pragma unroll 1" pins it (no compiler
//    unroll -> no reg growth). Latency hidden by TLP: 27 waves/CU (~84%
//    occupancy) instead of ILP ping-pong we can't afford registers for.
//  - twin o-group reads same x addresses -> L1/L2 hits, no extra HBM.
//  - A og-slice (16 KB) in LDS, uniform ds_read broadcasts; each group
//    reads its 8-o half. XCD-twin swizzle kept (og = blk bit 3).
// Need ~= 16 acc + 16 x + ~20 addr ~= 52 < 64. Numerics identical to R7.
// ---------------------------------------------------------------------------
__global__ __launch_bounds__(384) void k3_main(const float* __restrict__ x,
                                               const float* __restrict__ A,
                                               float* __restrict__ z,
                                               float* __restrict__ bnSum,
                                               float* __restrict__ bnSq) {
    __shared__ float sA[4096];          // og-slice: [c<32][o'<16][pqr<8]
    __shared__ float red[6][16];        // per-wave BN partials (8 sum + 8 sq)
    int blk  = blockIdx.x;             // [resthi | og(1b) | restlo(3b)]
    int og   = (blk >> 3) & 1;
    int rest = (blk & 7) | ((blk >> 4) << 3);   // 0..575
    int ohg  = rest % 6;
    int tmp  = rest / 6;
    int od   = tmp % 48;
    int b    = tmp / 48;
    int tid  = threadIdx.x;
    int ogrp = tid / 192;              // 0/1: which 8-o half of this og
    int tl   = tid % 192;
    int row = tl / 24;                 // 0..7
    int t   = tl % 24;                 // ow-pair: outputs 2t, 2t+1
    int oh  = ohg * 8 + row;

    const float4* x4 = (const float4*)x;
    // float4 index for (b, c, 2od+p, 2oh+q, 4t): channel stride 96^3/4 = 221184
    int base = (((b * 32) * 96 + 2 * od) * 96 + 2 * oh) * 24 + t;

    // stage A og-slice into LDS: sA[c*128 + o'*8 + pqr] = A[b][c][og*16+o'][pqr]
    {
        const float4* A4 = (const float4*)A;
        int srcbase = b * 2048 + og * 32;     // float4 units
        float4* sA4 = (float4*)sA;
        for (int s = tid; s < 1024; s += 384) {
            int c = s >> 5, j = s & 31;
            sA4[s] = A4[srcbase + c * 64 + j];
        }
    }

    float acc0[8], acc1[8];
#pragma unroll
    for (int o = 0; o < 8; ++o) { acc0[o] = 0.f; acc1[o] = 0.f; }

    __syncthreads();

    const float* Acg = sA + ogrp * 64;     // this group's 8-o half
#pragma unroll 1
    for (int c = 0; c < 32; ++c) {
        int i4 = base + c * 221184;
        float4 v00 = x4[i4];
        float4 v01 = x4[i4 + 24];
        float4 v10 = x4[i4 + 2304];
        float4 v11 = x4[i4 + 2328];
        const float* Ac = Acg + c * 128;
#pragma unroll
        for (int o = 0; o < 8; ++o) {
            const float* Ao = Ac + o * 8;   // uniform LDS broadcast
            float a0 = Ao[0], a1 = Ao[1], a2 = Ao[2], a3 = Ao[3];
            float a4 = Ao[4], a5 = Ao[5], a6 = Ao[6], a7 = Ao[7];
            acc0[o] += a0 * v00.x + a1 * v00.y + a2 * v01.x + a3 * v01.y
                     + a4 * v10.x + a5 * v10.y + a6 * v11.x + a7 * v11.y;
            acc1[o] += a0 * v00.z + a1 * v00.w + a2 * v01.z + a3 * v01.w
                     + a4 * v10.z + a5 * v10.w + a6 * v11.z + a7 * v11.w;
        }
    }

    // write z (staged in d_out), coalesced float2 per o
    float2* z2 = (float2*)z;
#pragma unroll
    for (int o = 0; o < 8; ++o) {
        int och = og * 16 + ogrp * 8 + o;
        int zi = (((b * 32 + och) * 48 + od) * 48 + oh) * 24 + t;
        z2[zi] = make_float2(acc0[o], acc1[o]);
    }

    // BN partial sums: each wave reduces its 8 o's (waves 0-2: ogrp0, 3-5: ogrp1)
    int lane = tid & 63, wave = tid >> 6;   // 0..5
#pragma unroll
    for (int o = 0; o < 8; ++o) {
        float sv = acc0[o] + acc1[o];
        float qv = acc0[o] * acc0[o] + acc1[o] * acc1[o];
#pragma unroll
        for (int m = 32; m; m >>= 1) {
            sv += __shfl_xor(sv, m, 64);
            qv += __shfl_xor(qv, m, 64);
        }
        if (lane == 0) { red[wave][o] = sv; red[wave][8 + o] = qv; }
    }
    __syncthreads();
    if (tid < 32) {
        int i   = tid & 7;
        int grp = (tid >> 3) & 1;
        int w0  = grp * 3;
        int off = (tid < 16) ? 0 : 8;
        float v = red[w0][off + i] + red[w0 + 1][off + i] + red[w0 + 2][off + i];
        int ch = og * 16 + grp * 8 + i;
        if (tid < 16) atomicAdd(&bnSum[ch], v);
        else          atomicAdd(&bnSq[ch], v);
    }
}

// ---------------------------------------------------------------------------
// K5: BN finalize (per-block recompute) + normalize + ReLU, in place over
// z (= d_out). 1769472 float4s exactly. b_fuse cancels under BN mean-subtract.
// ---------------------------------------------------------------------------
__global__ __launch_bounds__(256) void k5_norm(float* __restrict__ z,
                                               const float* __restrict__ bnSum,
                                               const float* __restrict__ bnSq,
                                               const float* __restrict__ gamma,
                                               const float* __restrict__ beta) {
    __shared__ float s_sc[32], s_sh[32];
    int tid = threadIdx.x;
    if (tid < 32) {
        const float invN = 1.f / (float)NBN;
        float mean = bnSum[tid] * invN;
        float var  = bnSq[tid] * invN - mean * mean;
        float inv  = rsqrtf(var + 1e-5f);
        float sc   = gamma[tid] * inv;
        s_sc[tid] = sc;
        s_sh[tid] = beta[tid] - mean * sc;
    }
    int i = blockIdx.x * 256 + tid;                // float4 index
    float4* z4 = (float4*)z;
    float4 v = z4[i];                              // load before barrier (indep)
    __syncthreads();
    int o = (i / 27648) & 31;                      // 27648 = 48^3/4
    float sc = s_sc[o], sh = s_sh[o];
    v.x = fmaxf(v.x * sc + sh, 0.f);
    v.y = fmaxf(v.y * sc + sh, 0.f);
    v.z = fmaxf(v.z * sc + sh, 0.f);
    v.w = fmaxf(v.w * sc + sh, 0.f);
    z4[i] = v;
}

extern "C" void kernel_launch(void* const* d_in, const int* in_sizes, int n_in,
                              void* d_out, int out_size, void* d_ws, size_t ws_size,
                              hipStream_t stream) {
    const float* x    = (const float*)d_in[0];
    const float* w1l  = (const float*)d_in[1];
    const float* w2l  = (const float*)d_in[2];
    const float* w1h  = (const float*)d_in[3];
    const float* w2h  = (const float*)d_in[4];
    const float* wf   = (const float*)d_in[5];
    // d_in[6] = b_fuse: cancels exactly under training-mode BN (mean subtract)
    const float* gamma = (const float*)d_in[7];
    const float* beta  = (const float*)d_in[8];
    float* out = (float*)d_out;

    float* ws    = (float*)d_ws;
    float* S     = ws;          // 512 floats (zeroed)
    float* bnSum = ws + 512;    // 32 (zeroed)
    float* bnSq  = ws + 544;    // 32 (zeroed)
    float* A     = ws + 1024;   // 16384 floats, layout [b][c][o][pqr]

    hipMemsetAsync(d_ws, 0, 576 * sizeof(float), stream);
    k1_parity<<<6144, 256, 0, stream>>>(x, S);
    k2_attn<<<16, 256, 0, stream>>>(S, w1l, w2l, w1h, w2h, wf, A);
    k3_main<<<1152, 384, 0, stream>>>(x, A, out, bnSum, bnSq);
    k5_norm<<<6912, 256, 0, stream>>>(out, bnSum, bnSq, gamma, beta);
}